// Round 1
// baseline (7338.495 us; speedup 1.0000x reference)
//
#include <hip/hip_runtime.h>
#include <math.h>

#define NN 512      // B*S
#define LL 128      // L
#define DM 256      // D_MODEL
#define DT 32       // D_TIME
#define DIN 288     // D_MODEL + D_TIME

static __device__ __forceinline__ unsigned short f2bf(float x){
  unsigned int u = __builtin_bit_cast(unsigned int, x);
  u += 0x7fffu + ((u >> 16) & 1u);          // RNE
  return (unsigned short)(u >> 16);
}
static __device__ __forceinline__ float bf2f(unsigned short u){
  return __builtin_bit_cast(float, ((unsigned int)u) << 16);
}

// ---------------------------------------------------------------- temporal emb
__global__ __launch_bounds__(256) void k_temporal(const float* __restrict__ tim,
                                                  float* __restrict__ tem){
  int idx = blockIdx.x * 256 + threadIdx.x;  // 512*128*16 total
  int i = idx & 15;
  int m = idx >> 4;                          // n*128 + j
  float t = tim[m];
  float np = (t > 0.0f) ? 1.0f : 0.0f;
  float dv = expf((float)(2 * i) * (-0.28782313662425576f)); // -ln(10000)/32
  float arg = t * dv;
  tem[m * DT + 2 * i]     = sinf(arg) * np;
  tem[m * DT + 2 * i + 1] = cosf(arg) * np;
}

// ---------------------------------------------------------------- input proj
// enc[m][col] = concat(ent[subj],ent[obj],rel[rel]) @ in_w + in_b   (bf16 out)
__global__ __launch_bounds__(256) void k_inproj(const int* __restrict__ subj,
    const int* __restrict__ obj, const int* __restrict__ rel,
    const float* __restrict__ ent, const float* __restrict__ rele,
    const float* __restrict__ in_w, const float* __restrict__ in_b,
    unsigned short* __restrict__ enc){
  __shared__ float A[16 * 384];
  int t = threadIdx.x;
  int m0 = blockIdx.x * 16;
  int r = t >> 4, lane = t & 15;
  int m = m0 + r;
  const float* sp = ent  + (size_t)subj[m] * 128;
  const float* op = ent  + (size_t)obj[m]  * 128;
  const float* rp = rele + (size_t)rel[m]  * 128;
  for (int c = lane; c < 128; c += 16){
    A[r * 384 + c]       = sp[c];
    A[r * 384 + 128 + c] = op[c];
    A[r * 384 + 256 + c] = rp[c];
  }
  __syncthreads();
  float acc[16];
#pragma unroll
  for (int i = 0; i < 16; i++) acc[i] = 0.0f;
  int col = t;
  for (int k4 = 0; k4 < 96; k4++){
    float b0 = in_w[(k4 * 4 + 0) * 256 + col];
    float b1 = in_w[(k4 * 4 + 1) * 256 + col];
    float b2 = in_w[(k4 * 4 + 2) * 256 + col];
    float b3 = in_w[(k4 * 4 + 3) * 256 + col];
#pragma unroll
    for (int rr = 0; rr < 16; rr++){
      const float4 a = *(const float4*)&A[rr * 384 + k4 * 4];
      acc[rr] = fmaf(a.x, b0, fmaf(a.y, b1, fmaf(a.z, b2, fmaf(a.w, b3, acc[rr]))));
    }
  }
  float bias = in_b[col];
#pragma unroll
  for (int rr = 0; rr < 16; rr++)
    enc[(size_t)(m0 + rr) * 256 + col] = f2bf(acc[rr] + bias);
}

// gather one ci row (288) into LDS: rows <128 from enc(bf16), >=128 from cur(f32)
static __device__ __forceinline__ void gather_ci_row(float* dst, int n, int row, int lane,
    const unsigned short* __restrict__ enc, const float* __restrict__ cur,
    const float* __restrict__ tem){
  int jr = (row < LL) ? row : (row - LL);
  const float* tr = tem + ((size_t)n * LL + jr) * DT;
  if (row < LL){
    const unsigned short* e = enc + ((size_t)n * LL + row) * DM;
    for (int c = lane; c < DM; c += 16) dst[c] = bf2f(e[c]);
  } else {
    const float* cr = cur + ((size_t)n * LL + (row - LL)) * DM;
    for (int c = lane; c < DM; c += 16) dst[c] = cr[c];
  }
  for (int c = lane; c < DT; c += 16) dst[DM + c] = tr[c];
}

// ---------------------------------------------------------------- K,V projection
// kT[n][c][row] (transposed, bf16), v[n][row][c] (bf16)
__global__ __launch_bounds__(256) void k_kv(const unsigned short* __restrict__ enc,
    const float* __restrict__ cur, const float* __restrict__ tem,
    const float* __restrict__ wk, const float* __restrict__ wv,
    const float* __restrict__ bk, const float* __restrict__ bv,
    unsigned short* __restrict__ kT, unsigned short* __restrict__ vg){
  __shared__ float A[16 * DIN];
  int t = threadIdx.x;
  int n  = blockIdx.x >> 4;
  int r0 = (blockIdx.x & 15) * 16;
  int r = t >> 4, lane = t & 15;
  gather_ci_row(&A[r * DIN], n, r0 + r, lane, enc, cur, tem);
  __syncthreads();
  float ak[16], av[16];
#pragma unroll
  for (int i = 0; i < 16; i++){ ak[i] = 0.0f; av[i] = 0.0f; }
  int col = t;
  for (int k4 = 0; k4 < 72; k4++){
    float k0 = wk[(k4 * 4 + 0) * 256 + col];
    float k1 = wk[(k4 * 4 + 1) * 256 + col];
    float k2 = wk[(k4 * 4 + 2) * 256 + col];
    float k3 = wk[(k4 * 4 + 3) * 256 + col];
    float v0 = wv[(k4 * 4 + 0) * 256 + col];
    float v1 = wv[(k4 * 4 + 1) * 256 + col];
    float v2 = wv[(k4 * 4 + 2) * 256 + col];
    float v3 = wv[(k4 * 4 + 3) * 256 + col];
#pragma unroll
    for (int rr = 0; rr < 16; rr++){
      const float4 a = *(const float4*)&A[rr * DIN + k4 * 4];
      ak[rr] = fmaf(a.x, k0, fmaf(a.y, k1, fmaf(a.z, k2, fmaf(a.w, k3, ak[rr]))));
      av[rr] = fmaf(a.x, v0, fmaf(a.y, v1, fmaf(a.z, v2, fmaf(a.w, v3, av[rr]))));
    }
  }
  float bkb = bk[col], bvb = bv[col];
#pragma unroll
  for (int rr = 0; rr < 16; rr++)
    vg[((size_t)n * 256 + r0 + rr) * 256 + col] = f2bf(av[rr] + bvb);
  unsigned int kp[8];
#pragma unroll
  for (int i = 0; i < 8; i++){
    unsigned int lo = f2bf(ak[2 * i]     + bkb);
    unsigned int hi = f2bf(ak[2 * i + 1] + bkb);
    kp[i] = (hi << 16) | lo;
  }
  uint4* dst = (uint4*)&kT[((size_t)n * 256 + col) * 256 + r0];
  dst[0] = make_uint4(kp[0], kp[1], kp[2], kp[3]);
  dst[1] = make_uint4(kp[4], kp[5], kp[6], kp[7]);
}

// ---------------------------------------------------------------- attention
// per block: one n, 16 query rows. Computes q on the fly, scores, softmax, PV,
// then writes enc rows (<L) / updates cur rows (>=L).
__global__ __launch_bounds__(256) void k_attn(unsigned short* __restrict__ enc,
    float* __restrict__ cur, const float* __restrict__ tem,
    const float* __restrict__ wq, const float* __restrict__ bq,
    const unsigned short* __restrict__ kT, const unsigned short* __restrict__ vg,
    const float* __restrict__ tim){
  __shared__ float CI[16 * DIN];   // 18 KB
  __shared__ float QS[16 * 256];   // 16 KB
  __shared__ float SS[16 * 256];   // 16 KB
  __shared__ float RS[16];
  int t = threadIdx.x;
  int n  = blockIdx.x >> 4;
  int q0 = (blockIdx.x & 15) * 16;
  int r = t >> 4, lane = t & 15;
  gather_ci_row(&CI[r * DIN], n, q0 + r, lane, enc, cur, tem);
  __syncthreads();
  int col = t;
  { // q = CI @ wq + bq  (fp32, into LDS)
    float aq[16];
#pragma unroll
    for (int i = 0; i < 16; i++) aq[i] = 0.0f;
    for (int k4 = 0; k4 < 72; k4++){
      float b0 = wq[(k4 * 4 + 0) * 256 + col];
      float b1 = wq[(k4 * 4 + 1) * 256 + col];
      float b2 = wq[(k4 * 4 + 2) * 256 + col];
      float b3 = wq[(k4 * 4 + 3) * 256 + col];
#pragma unroll
      for (int rr = 0; rr < 16; rr++){
        const float4 a = *(const float4*)&CI[rr * DIN + k4 * 4];
        aq[rr] = fmaf(a.x, b0, fmaf(a.y, b1, fmaf(a.z, b2, fmaf(a.w, b3, aq[rr]))));
      }
    }
    float bb = bq[col];
#pragma unroll
    for (int rr = 0; rr < 16; rr++) QS[rr * 256 + col] = aq[rr] + bb;
  }
  __syncthreads();
  // scores: thread = key
  int key = t;
  float tkey = (key < LL) ? tim[n * LL + key] : 1.0f;
  bool tz = (tkey == 0.0f);
  float acc[16];
#pragma unroll
  for (int i = 0; i < 16; i++) acc[i] = 0.0f;
  const unsigned short* kbase = kT + (size_t)n * 65536;
  for (int c4 = 0; c4 < 64; c4++){
    float k0 = bf2f(kbase[(c4 * 4 + 0) * 256 + key]);
    float k1 = bf2f(kbase[(c4 * 4 + 1) * 256 + key]);
    float k2 = bf2f(kbase[(c4 * 4 + 2) * 256 + key]);
    float k3 = bf2f(kbase[(c4 * 4 + 3) * 256 + key]);
#pragma unroll
    for (int rr = 0; rr < 16; rr++){
      const float4 a = *(const float4*)&QS[rr * 256 + c4 * 4];
      acc[rr] = fmaf(a.x, k0, fmaf(a.y, k1, fmaf(a.z, k2, fmaf(a.w, k3, acc[rr]))));
    }
  }
#pragma unroll
  for (int rr = 0; rr < 16; rr++){
    int Q = q0 + rr;
    bool masked;
    if (Q < LL) masked = (key >= Q) || (key >= LL) || tz;
    else {
      int qq = Q - LL;
      masked = (key < LL) ? ((key >= qq) || tz) : ((key - LL) != qq);
    }
    SS[rr * 256 + key] = masked ? -1.0e9f : acc[rr] * 0.0625f;
  }
  __syncthreads();
  { // softmax: 16 threads per row, shfl reductions within 16-lane groups
    int rr2 = t >> 4, j = t & 15;
    float vmax = -3.0e38f;
#pragma unroll
    for (int kk = 0; kk < 16; kk++) vmax = fmaxf(vmax, SS[rr2 * 256 + j * 16 + kk]);
#pragma unroll
    for (int mk = 1; mk < 16; mk <<= 1) vmax = fmaxf(vmax, __shfl_xor(vmax, mk, 64));
    float psum = 0.0f;
#pragma unroll
    for (int kk = 0; kk < 16; kk++){
      float e = expf(SS[rr2 * 256 + j * 16 + kk] - vmax);
      SS[rr2 * 256 + j * 16 + kk] = e;  // store unnormalized
      psum += e;
    }
#pragma unroll
    for (int mk = 1; mk < 16; mk <<= 1) psum += __shfl_xor(psum, mk, 64);
    if (j == 0) RS[rr2] = 1.0f / psum;
  }
  __syncthreads();
  // PV: thread = output col
  float out[16];
#pragma unroll
  for (int i = 0; i < 16; i++) out[i] = 0.0f;
  const unsigned short* vbase = vg + (size_t)n * 65536;
  for (int c4 = 0; c4 < 64; c4++){
    float v0 = bf2f(vbase[(c4 * 4 + 0) * 256 + col]);
    float v1 = bf2f(vbase[(c4 * 4 + 1) * 256 + col]);
    float v2 = bf2f(vbase[(c4 * 4 + 2) * 256 + col]);
    float v3 = bf2f(vbase[(c4 * 4 + 3) * 256 + col]);
#pragma unroll
    for (int rr = 0; rr < 16; rr++){
      const float4 p = *(const float4*)&SS[rr * 256 + c4 * 4];
      out[rr] = fmaf(p.x, v0, fmaf(p.y, v1, fmaf(p.z, v2, fmaf(p.w, v3, out[rr]))));
    }
  }
#pragma unroll
  for (int rr = 0; rr < 16; rr++){
    float o = out[rr] * RS[rr];
    int Q = q0 + rr;
    if (Q < LL){
      enc[((size_t)n * LL + Q) * 256 + col] = f2bf(o);
    } else {
      int qq = Q - LL;
      float tq = tim[n * LL + qq];
      float add = (tq > 0.0f) ? tanhf(o) : 0.0f;
      cur[((size_t)n * LL + qq) * 256 + col] += add;
    }
  }
}

// ---------------------------------------------------------------- save feat
__global__ __launch_bounds__(256) void k_savefeat(const float* __restrict__ cur,
                                                  float* __restrict__ feat, int h){
  int idx = blockIdx.x * 256 + threadIdx.x;   // 512*256
  int n = idx >> 8, c = idx & 255;
  feat[(size_t)n * 512 + h * 256 + c] = cur[((size_t)n * LL + (LL - 1)) * 256 + c];
}

// ---------------------------------------------------------------- output MLP
__global__ __launch_bounds__(256) void k_mlp(const float* __restrict__ feat,
    const float* __restrict__ w1, const float* __restrict__ b1,
    const float* __restrict__ w2, const float* __restrict__ b2,
    float* __restrict__ out){
  __shared__ float F[512];
  __shared__ float red[4];
  int n = blockIdx.x, t = threadIdx.x;
  F[t]       = feat[(size_t)n * 512 + t];
  F[t + 256] = feat[(size_t)n * 512 + 256 + t];
  __syncthreads();
  float acc = 0.0f;
  for (int k4 = 0; k4 < 128; k4++){
    float b0v = w1[(k4 * 4 + 0) * 256 + t];
    float b1v = w1[(k4 * 4 + 1) * 256 + t];
    float b2v = w1[(k4 * 4 + 2) * 256 + t];
    float b3v = w1[(k4 * 4 + 3) * 256 + t];
    const float4 f = *(const float4*)&F[k4 * 4];
    acc = fmaf(f.x, b0v, fmaf(f.y, b1v, fmaf(f.z, b2v, fmaf(f.w, b3v, acc))));
  }
  acc += b1[t];
  float g = 0.5f * acc * (1.0f + erff(acc * 0.7071067811865475f)); // exact gelu
  float part = g * w2[t];
#pragma unroll
  for (int mk = 1; mk < 64; mk <<= 1) part += __shfl_xor(part, mk, 64);
  if ((t & 63) == 0) red[t >> 6] = part;
  __syncthreads();
  if (t == 0) out[n] = red[0] + red[1] + red[2] + red[3] + b2[0];
}

// ---------------------------------------------------------------- launch
extern "C" void kernel_launch(void* const* d_in, const int* in_sizes, int n_in,
                              void* d_out, int out_size, void* d_ws, size_t ws_size,
                              hipStream_t stream){
  const int*   subj = (const int*)  d_in[0];
  const int*   obj  = (const int*)  d_in[1];
  const int*   rel  = (const int*)  d_in[2];
  const float* tim  = (const float*)d_in[3];
  const float* ent  = (const float*)d_in[4];
  const float* rele = (const float*)d_in[5];
  const float* in_w = (const float*)d_in[6];
  const float* in_b = (const float*)d_in[7];
  const float* q_w  = (const float*)d_in[8];
  const float* q_b  = (const float*)d_in[9];
  const float* k_w  = (const float*)d_in[10];
  const float* k_b  = (const float*)d_in[11];
  const float* v_w  = (const float*)d_in[12];
  const float* v_b  = (const float*)d_in[13];
  const float* w1   = (const float*)d_in[14];
  const float* b1   = (const float*)d_in[15];
  const float* w2   = (const float*)d_in[16];
  const float* b2   = (const float*)d_in[17];

  // ws layout (233 MiB total)
  char* ws = (char*)d_ws;
  float*          tem  = (float*)ws;                               //  8,388,608 B
  float*          cur  = (float*)(ws + 8388608);                   // 67,108,864 B
  unsigned short* enc  = (unsigned short*)(ws + 75497472);         // 33,554,432 B
  unsigned short* kT   = (unsigned short*)(ws + 109051904);        // 67,108,864 B
  unsigned short* vg   = (unsigned short*)(ws + 176160768);        // 67,108,864 B
  float*          feat = (float*)(ws + 243269632);                 //  1,048,576 B
  float* out = (float*)d_out;

  k_temporal<<<4096, 256, 0, stream>>>(tim, tem);
  hipMemsetAsync(cur, 0, 67108864, stream);
  k_inproj<<<4096, 256, 0, stream>>>(subj, obj, rel, ent, rele, in_w, in_b, enc);

  for (int h = 0; h < 2; h++){
    for (int l = 0; l < 2; l++){
      int o = h * 2 + l;
      k_kv<<<8192, 256, 0, stream>>>(enc, cur, tem,
          k_w + (size_t)o * DIN * DM, v_w + (size_t)o * DIN * DM,
          k_b + o * DM, v_b + o * DM, kT, vg);
      k_attn<<<8192, 256, 0, stream>>>(enc, cur, tem,
          q_w + (size_t)o * DIN * DM, q_b + o * DM, kT, vg, tim);
    }
    k_savefeat<<<512, 256, 0, stream>>>(cur, feat, h);
    if (h == 0) hipMemsetAsync(cur, 0, 67108864, stream);
  }
  k_mlp<<<512, 256, 0, stream>>>(feat, w1, b1, w2, b2, out);
}

// Round 2
// 1843.240 us; speedup vs baseline: 3.9813x; 3.9813x over previous
//
#include <hip/hip_runtime.h>
#include <math.h>

typedef __bf16 bf16x8 __attribute__((ext_vector_type(8)));
typedef float  f32x16 __attribute__((ext_vector_type(16)));

static __device__ __forceinline__ f32x16 MFMA(bf16x8 a, bf16x8 b, f32x16 c){
  return __builtin_amdgcn_mfma_f32_32x32x16_bf16(a, b, c, 0, 0, 0);
}
static __device__ __forceinline__ unsigned short f2bf(float x){
  unsigned int u = __builtin_bit_cast(unsigned int, x);
  u += 0x7fffu + ((u >> 16) & 1u);   // RNE
  return (unsigned short)(u >> 16);
}
static __device__ __forceinline__ unsigned int pack2(float a, float b){
  return ((unsigned int)f2bf(b) << 16) | (unsigned int)f2bf(a);
}
static __device__ __forceinline__ bf16x8 ldfrag(const unsigned short* p){
  return __builtin_bit_cast(bf16x8, *(const uint4*)p);
}
// C-layout row for 32x32x16: row = (reg&3) + 8*(reg>>2) + 4*(lane>>5)
static __device__ __forceinline__ int rowmap(int reg, int lane){
  return (reg & 3) + 8 * (reg >> 2) + 4 * (lane >> 5);
}

// ------------------------------------------------ weight transpose+cast (once)
// wT layout: [0..98303]  in_wT[256][384]
//            then 12 matrices m=(h*2+l)*3+p (p=0:q,1:k,2:v): [256][288] each
__global__ __launch_bounds__(256) void k_wprep(const float* __restrict__ in_w,
    const float* __restrict__ q_w, const float* __restrict__ k_w,
    const float* __restrict__ v_w, unsigned short* __restrict__ wT){
  int idx = blockIdx.x * 256 + threadIdx.x;   // 983040 total
  float v;
  if (idx < 98304){
    int c = idx / 384, k = idx % 384;
    v = in_w[k * 256 + c];
  } else {
    int e = idx - 98304;
    int m = e / 73728, r = e % 73728;
    int c = r / 288, k = r % 288;
    int p = m % 3, layer = m / 3;
    const float* src = (p == 0) ? q_w : (p == 1) ? k_w : v_w;
    v = src[(size_t)layer * 73728 + k * 256 + c];
  }
  wT[idx] = f2bf(v);
}

// ------------------------------------------------ temporal emb (bf16, masked)
__global__ __launch_bounds__(256) void k_temporal(const float* __restrict__ tim,
                                                  unsigned int* __restrict__ tem){
  int idx = blockIdx.x * 256 + threadIdx.x;   // 65536*16
  int i = idx & 15, m = idx >> 4;
  float t = tim[m];
  float np = (t > 0.0f) ? 1.0f : 0.0f;
  float dv = expf((float)(2 * i) * (-0.28782313662425576f));
  float arg = t * dv;
  tem[m * 16 + i] = pack2(sinf(arg) * np, cosf(arg) * np);
}

// ------------------------------------------------ input projection (MFMA)
__global__ __launch_bounds__(256, 2) void k_inproj(const int* __restrict__ subj,
    const int* __restrict__ obj, const int* __restrict__ rel,
    const float* __restrict__ ent, const float* __restrict__ rele,
    const unsigned short* __restrict__ inwT, const float* __restrict__ in_b,
    unsigned short* __restrict__ enc){
  __shared__ __align__(16) unsigned short A[64 * 392];
  int t = threadIdx.x;
  int m0 = blockIdx.x * 64;
  { // gather 64 rows of concat(ent[s],ent[o],rel[r]) as bf16
    int r = t >> 2, c = t & 3;
    int m = m0 + r;
    const float4* s0 = (const float4*)(ent  + (size_t)subj[m] * 128 + c * 32);
    const float4* s1 = (const float4*)(ent  + (size_t)obj[m]  * 128 + c * 32);
    const float4* s2 = (const float4*)(rele + (size_t)rel[m]  * 128 + c * 32);
    unsigned int* dst = (unsigned int*)&A[r * 392];
#pragma unroll
    for (int j = 0; j < 8; j++){
      float4 f0 = s0[j], f1 = s1[j], f2 = s2[j];
      dst[c * 16 + 2 * j]           = pack2(f0.x, f0.y);
      dst[c * 16 + 2 * j + 1]       = pack2(f0.z, f0.w);
      dst[64 + c * 16 + 2 * j]      = pack2(f1.x, f1.y);
      dst[64 + c * 16 + 2 * j + 1]  = pack2(f1.z, f1.w);
      dst[128 + c * 16 + 2 * j]     = pack2(f2.x, f2.y);
      dst[128 + c * 16 + 2 * j + 1] = pack2(f2.z, f2.w);
    }
  }
  __syncthreads();
  int w = t >> 6, lane = t & 63;
  int lrow = lane & 31, khalf = (lane >> 5) * 8;
  int ct0 = w * 2;
  f32x16 acc[2][2] = {};
  for (int ks = 0; ks < 24; ks++){
    int koff = ks * 16 + khalf;
    bf16x8 a0 = ldfrag(&A[lrow * 392 + koff]);
    bf16x8 a1 = ldfrag(&A[(32 + lrow) * 392 + koff]);
    bf16x8 b0 = ldfrag(&inwT[(size_t)(ct0 * 32 + lrow) * 384 + koff]);
    bf16x8 b1 = ldfrag(&inwT[(size_t)(ct0 * 32 + 32 + lrow) * 384 + koff]);
    acc[0][0] = MFMA(a0, b0, acc[0][0]);
    acc[1][0] = MFMA(a1, b0, acc[1][0]);
    acc[0][1] = MFMA(a0, b1, acc[0][1]);
    acc[1][1] = MFMA(a1, b1, acc[1][1]);
  }
  float bs0 = in_b[ct0 * 32 + lrow], bs1 = in_b[ct0 * 32 + 32 + lrow];
#pragma unroll
  for (int rt = 0; rt < 2; rt++)
#pragma unroll
    for (int reg = 0; reg < 16; reg++){
      size_t row = m0 + rt * 32 + rowmap(reg, lane);
      enc[row * 256 + ct0 * 32 + lrow]      = f2bf(acc[rt][0][reg] + bs0);
      enc[row * 256 + ct0 * 32 + 32 + lrow] = f2bf(acc[rt][1][reg] + bs1);
    }
}

// ------------------------------------------------ Q,K,V projections (MFMA)
// outputs (chunk-local nn in [0,256)): qb/kb plain [nn][row][col] bf16,
// vtb transposed [nn][d][key] bf16
__global__ __launch_bounds__(256, 2) void k_qkv(const unsigned short* __restrict__ enc,
    const float* __restrict__ cur, const unsigned short* __restrict__ tem,
    const unsigned short* __restrict__ wq, const unsigned short* __restrict__ wk,
    const unsigned short* __restrict__ wv, const float* __restrict__ bq,
    const float* __restrict__ bk, const float* __restrict__ bv, int chunk,
    unsigned short* __restrict__ qb, unsigned short* __restrict__ kb,
    unsigned short* __restrict__ vtb){
  __shared__ __align__(16) unsigned short A[64 * 296];
  __shared__ unsigned short VT[256 * 66];
  int t = threadIdx.x;
  int nn = blockIdx.x >> 2;
  int n  = chunk * 256 + nn;
  int r0 = (blockIdx.x & 3) * 64;
  { // gather 64 ci rows -> bf16 LDS (stride 296)
    int r = t >> 2, c4 = t & 3;
    int grow = r0 + r;
    unsigned int* dst = (unsigned int*)&A[r * 296];
    if (grow < 128){
      const uint4* s4 = (const uint4*)(enc + ((size_t)n * 128 + grow) * 256 + c4 * 64);
      uint4* d4 = (uint4*)(dst + c4 * 32);
#pragma unroll
      for (int j = 0; j < 8; j++) d4[j] = s4[j];
    } else {
      const float4* s4 = (const float4*)(cur + ((size_t)n * 128 + grow - 128) * 256 + c4 * 64);
      unsigned int* d = dst + c4 * 32;
#pragma unroll
      for (int j = 0; j < 16; j++){
        float4 f = s4[j];
        d[2 * j]     = pack2(f.x, f.y);
        d[2 * j + 1] = pack2(f.z, f.w);
      }
    }
    int jr = (grow < 128) ? grow : grow - 128;
    const uint4* ts = (const uint4*)(tem + ((size_t)n * 128 + jr) * 32);
    ((uint4*)(dst + 128))[c4] = ts[c4];
  }
  __syncthreads();
  int w = t >> 6, lane = t & 63;
  int lrow = lane & 31, khalf = (lane >> 5) * 8;
  int ct0 = w * 2;
  for (int p = 0; p < 3; p++){
    const unsigned short* B = (p == 0) ? wq : (p == 1) ? wk : wv;
    f32x16 acc[2][2] = {};
    for (int ks = 0; ks < 18; ks++){
      int koff = ks * 16 + khalf;
      bf16x8 a0 = ldfrag(&A[lrow * 296 + koff]);
      bf16x8 a1 = ldfrag(&A[(32 + lrow) * 296 + koff]);
      bf16x8 b0 = ldfrag(&B[(size_t)(ct0 * 32 + lrow) * 288 + koff]);
      bf16x8 b1 = ldfrag(&B[(size_t)(ct0 * 32 + 32 + lrow) * 288 + koff]);
      acc[0][0] = MFMA(a0, b0, acc[0][0]);
      acc[1][0] = MFMA(a1, b0, acc[1][0]);
      acc[0][1] = MFMA(a0, b1, acc[0][1]);
      acc[1][1] = MFMA(a1, b1, acc[1][1]);
    }
    const float* bias = (p == 0) ? bq : (p == 1) ? bk : bv;
    float bs0 = bias[ct0 * 32 + lrow], bs1 = bias[ct0 * 32 + 32 + lrow];
    if (p < 2){
      unsigned short* out = (p == 0) ? qb : kb;
#pragma unroll
      for (int rt = 0; rt < 2; rt++)
#pragma unroll
        for (int reg = 0; reg < 16; reg++){
          size_t base = ((size_t)nn * 256 + r0 + rt * 32 + rowmap(reg, lane)) * 256;
          out[base + ct0 * 32 + lrow]      = f2bf(acc[rt][0][reg] + bs0);
          out[base + ct0 * 32 + 32 + lrow] = f2bf(acc[rt][1][reg] + bs1);
        }
    } else {
#pragma unroll
      for (int rt = 0; rt < 2; rt++)
#pragma unroll
        for (int reg = 0; reg < 16; reg++){
          int kl = rt * 32 + rowmap(reg, lane);
          VT[(ct0 * 32 + lrow) * 66 + kl]      = f2bf(acc[rt][0][reg] + bs0);
          VT[(ct0 * 32 + 32 + lrow) * 66 + kl] = f2bf(acc[rt][1][reg] + bs1);
        }
    }
  }
  __syncthreads();
  { // VT -> vtb[nn][d][r0..r0+63]
    const unsigned int* vs = (const unsigned int*)&VT[t * 66];
    uint4* gd = (uint4*)(vtb + ((size_t)nn * 256 + t) * 256 + r0);
#pragma unroll
    for (int j = 0; j < 8; j++)
      gd[j] = make_uint4(vs[4 * j], vs[4 * j + 1], vs[4 * j + 2], vs[4 * j + 3]);
  }
}

// ------------------------------------------------ attention (MFMA flash-style)
__global__ __launch_bounds__(256, 2) void k_attn(const unsigned short* __restrict__ qb,
    const unsigned short* __restrict__ kb, const unsigned short* __restrict__ vtb,
    unsigned short* __restrict__ enc, float* __restrict__ cur,
    const float* __restrict__ tim, int chunk){
  __shared__ __align__(16) unsigned short PB[4][32 * 264];
  __shared__ float TS[128];
  int t = threadIdx.x;
  int nn = blockIdx.x >> 1;
  int n  = chunk * 256 + nn;
  int q0 = (blockIdx.x & 1) * 128;
  if (t < 128) TS[t] = tim[(size_t)n * 128 + t];
  __syncthreads();
  int w = t >> 6, lane = t & 63;
  int lrow = lane & 31, khalf = (lane >> 5) * 8;
  int qrow = q0 + w * 32;
  const unsigned short* qn = qb  + (size_t)nn * 65536;
  const unsigned short* kn = kb  + (size_t)nn * 65536;
  const unsigned short* vn = vtb + (size_t)nn * 65536;
  // ---- scores: S = Q K^T  (per wave: 32 q x 256 keys)
  f32x16 s[8] = {};
  for (int ks = 0; ks < 16; ks++){
    int koff = ks * 16 + khalf;
    bf16x8 a = ldfrag(&qn[(size_t)(qrow + lrow) * 256 + koff]);
#pragma unroll
    for (int ct = 0; ct < 8; ct++){
      bf16x8 b = ldfrag(&kn[(size_t)(ct * 32 + lrow) * 256 + koff]);
      s[ct] = MFMA(a, b, s[ct]);
    }
  }
  // key-time-zero flags (keys < 128 only)
  bool tz[8];
#pragma unroll
  for (int ct = 0; ct < 8; ct++)
    tz[ct] = (ct < 4) ? (TS[ct * 32 + lrow] == 0.0f) : false;
  // ---- mask + softmax per row, write P (bf16) to per-wave LDS buffer
  unsigned short* myP = PB[w];
  bool xw = (qrow < 128);   // wave-uniform
#pragma unroll
  for (int reg = 0; reg < 16; reg++){
    int rl = rowmap(reg, lane);
    int Q = qrow + rl;
    float v[8];
#pragma unroll
    for (int ct = 0; ct < 8; ct++){
      int key = ct * 32 + lrow;
      bool masked;
      if (xw)  masked = (key >= Q) || (key >= 128) || tz[ct];
      else {
        int qq = Q - 128;
        masked = (key < 128) ? ((key >= qq) || tz[ct]) : ((key - 128) != qq);
      }
      v[ct] = masked ? -1.0e9f : s[ct][reg] * 0.0625f;
    }
    float m = v[0];
#pragma unroll
    for (int ct = 1; ct < 8; ct++) m = fmaxf(m, v[ct]);
#pragma unroll
    for (int mk = 1; mk <= 16; mk <<= 1) m = fmaxf(m, __shfl_xor(m, mk, 64));
    float sum = 0.0f, e[8];
#pragma unroll
    for (int ct = 0; ct < 8; ct++){ e[ct] = __expf(v[ct] - m); sum += e[ct]; }
#pragma unroll
    for (int mk = 1; mk <= 16; mk <<= 1) sum += __shfl_xor(sum, mk, 64);
    float rs = 1.0f / sum;
#pragma unroll
    for (int ct = 0; ct < 8; ct++)
      myP[rl * 264 + ct * 32 + lrow] = f2bf(e[ct] * rs);
  }
  // ---- PV  (per wave: 32 q x 256 d)
  f32x16 ov[8] = {};
  for (int ks = 0; ks < 16; ks++){
    int koff = ks * 16 + khalf;
    bf16x8 a = ldfrag(&myP[lrow * 264 + koff]);
#pragma unroll
    for (int dt = 0; dt < 8; dt++){
      bf16x8 b = ldfrag(&vn[(size_t)(dt * 32 + lrow) * 256 + koff]);
      ov[dt] = MFMA(a, b, ov[dt]);
    }
  }
  // ---- epilogue
#pragma unroll
  for (int reg = 0; reg < 16; reg++){
    int rl = rowmap(reg, lane);
    int Q = qrow + rl;
    if (xw){
      size_t base = ((size_t)n * 128 + Q) * 256;
#pragma unroll
      for (int dt = 0; dt < 8; dt++)
        enc[base + dt * 32 + lrow] = f2bf(ov[dt][reg]);
    } else {
      int qq = Q - 128;
      float tq = TS[qq];
      size_t base = ((size_t)n * 128 + qq) * 256;
      if (tq > 0.0f){
#pragma unroll
        for (int dt = 0; dt < 8; dt++){
          float x = ov[dt][reg];
          float ex = __expf(2.0f * x);
          cur[base + dt * 32 + lrow] += 1.0f - 2.0f / (ex + 1.0f);  // tanh
        }
      }
    }
  }
}

// ------------------------------------------------ save feat (cur at j=L-1)
__global__ __launch_bounds__(256) void k_savefeat(const float* __restrict__ cur,
                                                  float* __restrict__ feat, int h){
  int idx = blockIdx.x * 256 + threadIdx.x;   // 512*256
  int n = idx >> 8, c = idx & 255;
  feat[(size_t)n * 512 + h * 256 + c] = cur[((size_t)n * 128 + 127) * 256 + c];
}

// ------------------------------------------------ output MLP head
__global__ __launch_bounds__(256) void k_mlp(const float* __restrict__ feat,
    const float* __restrict__ w1, const float* __restrict__ b1,
    const float* __restrict__ w2, const float* __restrict__ b2,
    float* __restrict__ out){
  __shared__ float F[512];
  __shared__ float red[4];
  int n = blockIdx.x, t = threadIdx.x;
  F[t]       = feat[(size_t)n * 512 + t];
  F[t + 256] = feat[(size_t)n * 512 + 256 + t];
  __syncthreads();
  float acc = 0.0f;
  for (int k4 = 0; k4 < 128; k4++){
    float b0v = w1[(k4 * 4 + 0) * 256 + t];
    float b1v = w1[(k4 * 4 + 1) * 256 + t];
    float b2v = w1[(k4 * 4 + 2) * 256 + t];
    float b3v = w1[(k4 * 4 + 3) * 256 + t];
    const float4 f = *(const float4*)&F[k4 * 4];
    acc = fmaf(f.x, b0v, fmaf(f.y, b1v, fmaf(f.z, b2v, fmaf(f.w, b3v, acc))));
  }
  acc += b1[t];
  float g = 0.5f * acc * (1.0f + erff(acc * 0.7071067811865475f));
  float part = g * w2[t];
#pragma unroll
  for (int mk = 1; mk < 64; mk <<= 1) part += __shfl_xor(part, mk, 64);
  if ((t & 63) == 0) red[t >> 6] = part;
  __syncthreads();
  if (t == 0) out[n] = red[0] + red[1] + red[2] + red[3] + b2[0];
}

// ------------------------------------------------ launch
extern "C" void kernel_launch(void* const* d_in, const int* in_sizes, int n_in,
                              void* d_out, int out_size, void* d_ws, size_t ws_size,
                              hipStream_t stream){
  const int*   subj = (const int*)  d_in[0];
  const int*   obj  = (const int*)  d_in[1];
  const int*   rel  = (const int*)  d_in[2];
  const float* tim  = (const float*)d_in[3];
  const float* ent  = (const float*)d_in[4];
  const float* rele = (const float*)d_in[5];
  const float* in_w = (const float*)d_in[6];
  const float* in_b = (const float*)d_in[7];
  const float* q_w  = (const float*)d_in[8];
  const float* q_b  = (const float*)d_in[9];
  const float* k_w  = (const float*)d_in[10];
  const float* k_b  = (const float*)d_in[11];
  const float* v_w  = (const float*)d_in[12];
  const float* v_b  = (const float*)d_in[13];
  const float* w1   = (const float*)d_in[14];
  const float* b1   = (const float*)d_in[15];
  const float* w2   = (const float*)d_in[16];
  const float* b2   = (const float*)d_in[17];

  char* ws = (char*)d_ws;                                   // 199 MiB total
  unsigned short* tem  = (unsigned short*)(ws + 0);         //  4,194,304
  float*          cur  = (float*)(ws + 4194304);            // 67,108,864
  unsigned short* enc  = (unsigned short*)(ws + 71303168);  // 33,554,432
  unsigned short* qb   = (unsigned short*)(ws + 104857600); // 33,554,432
  unsigned short* kb   = (unsigned short*)(ws + 138412032); // 33,554,432
  unsigned short* vtb  = (unsigned short*)(ws + 171966464); // 33,554,432
  float*          feat = (float*)(ws + 205520896);          //  1,048,576
  unsigned short* wT   = (unsigned short*)(ws + 206569472); //  1,966,080
  float* out = (float*)d_out;

  k_wprep<<<3840, 256, 0, stream>>>(in_w, q_w, k_w, v_w, wT);
  k_temporal<<<4096, 256, 0, stream>>>(tim, (unsigned int*)tem);
  hipMemsetAsync(cur, 0, 67108864, stream);
  k_inproj<<<1024, 256, 0, stream>>>(subj, obj, rel, ent, rele, wT, in_b, enc);

  for (int h = 0; h < 2; h++){
    for (int l = 0; l < 2; l++){
      int o = h * 2 + l;
      const unsigned short* wq = wT + 98304 + (size_t)(o * 3 + 0) * 73728;
      const unsigned short* wk = wT + 98304 + (size_t)(o * 3 + 1) * 73728;
      const unsigned short* wv = wT + 98304 + (size_t)(o * 3 + 2) * 73728;
      for (int c = 0; c < 2; c++){
        k_qkv<<<1024, 256, 0, stream>>>(enc, cur, tem, wq, wk, wv,
            q_b + o * 256, k_b + o * 256, v_b + o * 256, c, qb, kb, vtb);
        k_attn<<<512, 256, 0, stream>>>(qb, kb, vtb, enc, cur, tim, c);
      }
    }
    k_savefeat<<<512, 256, 0, stream>>>(cur, feat, h);
    if (h == 0) hipMemsetAsync(cur, 0, 67108864, stream);
  }
  k_mlp<<<512, 256, 0, stream>>>(feat, w1, b1, w2, b2, out);
}

// Round 3
// 1525.571 us; speedup vs baseline: 4.8103x; 1.2082x over previous
//
#include <hip/hip_runtime.h>
#include <math.h>

typedef __bf16 bf16x8 __attribute__((ext_vector_type(8)));
typedef float  f32x16 __attribute__((ext_vector_type(16)));

static __device__ __forceinline__ f32x16 MFMA(bf16x8 a, bf16x8 b, f32x16 c){
  return __builtin_amdgcn_mfma_f32_32x32x16_bf16(a, b, c, 0, 0, 0);
}
static __device__ __forceinline__ unsigned short f2bf(float x){
  unsigned int u = __builtin_bit_cast(unsigned int, x);
  u += 0x7fffu + ((u >> 16) & 1u);   // RNE
  return (unsigned short)(u >> 16);
}
static __device__ __forceinline__ unsigned int pack2(float a, float b){
  return ((unsigned int)f2bf(b) << 16) | (unsigned int)f2bf(a);
}
static __device__ __forceinline__ bf16x8 ldfrag(const unsigned short* p){
  return __builtin_bit_cast(bf16x8, *(const uint4*)p);
}
// C-layout row for 32x32x16: row = (reg&3) + 8*(reg>>2) + 4*(lane>>5)
static __device__ __forceinline__ int rowmap(int reg, int lane){
  return (reg & 3) + 8 * (reg >> 2) + 4 * (lane >> 5);
}

// ------------------------------------------------ weight transpose+cast (once)
__global__ __launch_bounds__(256) void k_wprep(const float* __restrict__ in_w,
    const float* __restrict__ q_w, const float* __restrict__ k_w,
    const float* __restrict__ v_w, unsigned short* __restrict__ wT){
  int idx = blockIdx.x * 256 + threadIdx.x;   // 983040 total
  float v;
  if (idx < 98304){
    int c = idx / 384, k = idx % 384;
    v = in_w[k * 256 + c];
  } else {
    int e = idx - 98304;
    int m = e / 73728, r = e % 73728;
    int c = r / 288, k = r % 288;
    int p = m % 3, layer = m / 3;
    const float* src = (p == 0) ? q_w : (p == 1) ? k_w : v_w;
    v = src[(size_t)layer * 73728 + k * 256 + c];
  }
  wT[idx] = f2bf(v);
}

// ------------------------------------------------ temporal emb (bf16, masked)
__global__ __launch_bounds__(256) void k_temporal(const float* __restrict__ tim,
                                                  unsigned int* __restrict__ tem){
  int idx = blockIdx.x * 256 + threadIdx.x;   // 65536*16
  int i = idx & 15, m = idx >> 4;
  float t = tim[m];
  float np = (t > 0.0f) ? 1.0f : 0.0f;
  float dv = expf((float)(2 * i) * (-0.28782313662425576f));
  float arg = t * dv;
  tem[m * 16 + i] = pack2(sinf(arg) * np, cosf(arg) * np);
}

// ------------------------------------------------ input projection (MFMA)
__global__ __launch_bounds__(256, 2) void k_inproj(const int* __restrict__ subj,
    const int* __restrict__ obj, const int* __restrict__ rel,
    const float* __restrict__ ent, const float* __restrict__ rele,
    const unsigned short* __restrict__ inwT, const float* __restrict__ in_b,
    unsigned short* __restrict__ enc){
  __shared__ __align__(16) unsigned short A[64 * 392];  // reused as SB[64*264] after
  int t = threadIdx.x;
  int m0 = blockIdx.x * 64;
  { // gather 64 rows of concat(ent[s],ent[o],rel[r]) as bf16
    int r = t >> 2, c = t & 3;
    int m = m0 + r;
    const float4* s0 = (const float4*)(ent  + (size_t)subj[m] * 128 + c * 32);
    const float4* s1 = (const float4*)(ent  + (size_t)obj[m]  * 128 + c * 32);
    const float4* s2 = (const float4*)(rele + (size_t)rel[m]  * 128 + c * 32);
    unsigned int* dst = (unsigned int*)&A[r * 392];
#pragma unroll
    for (int j = 0; j < 8; j++){
      float4 f0 = s0[j], f1 = s1[j], f2 = s2[j];
      dst[c * 16 + 2 * j]           = pack2(f0.x, f0.y);
      dst[c * 16 + 2 * j + 1]       = pack2(f0.z, f0.w);
      dst[64 + c * 16 + 2 * j]      = pack2(f1.x, f1.y);
      dst[64 + c * 16 + 2 * j + 1]  = pack2(f1.z, f1.w);
      dst[128 + c * 16 + 2 * j]     = pack2(f2.x, f2.y);
      dst[128 + c * 16 + 2 * j + 1] = pack2(f2.z, f2.w);
    }
  }
  __syncthreads();
  int w = t >> 6, lane = t & 63;
  int lrow = lane & 31, khalf = (lane >> 5) * 8;
  int colA = (w * 2) * 32 + lrow, colB = colA + 32;
  f32x16 acc[2][2] = {};
  bf16x8 pb0 = ldfrag(&inwT[(size_t)colA * 384 + khalf]);
  bf16x8 pb1 = ldfrag(&inwT[(size_t)colB * 384 + khalf]);
  for (int ks = 0; ks < 24; ks++){
    int koff = ks * 16 + khalf;
    bf16x8 a0 = ldfrag(&A[lrow * 392 + koff]);
    bf16x8 a1 = ldfrag(&A[(32 + lrow) * 392 + koff]);
    bf16x8 b0 = pb0, b1 = pb1;
    if (ks < 23){
      pb0 = ldfrag(&inwT[(size_t)colA * 384 + koff + 16]);
      pb1 = ldfrag(&inwT[(size_t)colB * 384 + koff + 16]);
    }
    acc[0][0] = MFMA(a0, b0, acc[0][0]);
    acc[1][0] = MFMA(a1, b0, acc[1][0]);
    acc[0][1] = MFMA(a0, b1, acc[0][1]);
    acc[1][1] = MFMA(a1, b1, acc[1][1]);
  }
  float bs0 = in_b[colA], bs1 = in_b[colB];
  __syncthreads();            // A dead; reuse as SB[64][264]
#pragma unroll
  for (int rt = 0; rt < 2; rt++)
#pragma unroll
    for (int reg = 0; reg < 16; reg++){
      int row = rt * 32 + rowmap(reg, lane);
      A[row * 264 + colA] = f2bf(acc[rt][0][reg] + bs0);
      A[row * 264 + colB] = f2bf(acc[rt][1][reg] + bs1);
    }
  __syncthreads();
  {
    int r = t >> 2, s = t & 3;
    const uint4* src = (const uint4*)&A[r * 264 + s * 64];
    uint4* dst = (uint4*)(enc + ((size_t)m0 + r) * 256 + s * 64);
#pragma unroll
    for (int j = 0; j < 8; j++) dst[j] = src[j];
  }
}

// ------------------------------------------------ Q,K,V projections (MFMA)
// qb/kb plain [nn][row][col] bf16 (coalesced via LDS), vtb transposed [nn][d][key]
__global__ __launch_bounds__(256, 2) void k_qkv(const unsigned short* __restrict__ enc,
    const float* __restrict__ cur, const unsigned short* __restrict__ tem,
    const unsigned short* __restrict__ wq, const unsigned short* __restrict__ wk,
    const unsigned short* __restrict__ wv, const float* __restrict__ bq,
    const float* __restrict__ bk, const float* __restrict__ bv,
    int chunk, int lzero,
    unsigned short* __restrict__ qb, unsigned short* __restrict__ kb,
    unsigned short* __restrict__ vtb){
  __shared__ __align__(16) unsigned short A[64 * 296];   // 37,888 B
  __shared__ __align__(16) unsigned short SB[64 * 264];  // 33,792 B (=VT[256*66])
  int t = threadIdx.x;
  int nn = blockIdx.x >> 2;
  int n  = chunk * 256 + nn;
  int r0 = (blockIdx.x & 3) * 64;
  { // gather 64 ci rows -> bf16 LDS (stride 296)
    int r = t >> 2, c4 = t & 3;
    int grow = r0 + r;
    unsigned int* dst = (unsigned int*)&A[r * 296];
    if (grow < 128){
      const uint4* s4 = (const uint4*)(enc + ((size_t)n * 128 + grow) * 256 + c4 * 64);
      uint4* d4 = (uint4*)(dst + c4 * 32);
#pragma unroll
      for (int j = 0; j < 8; j++) d4[j] = s4[j];
    } else if (!lzero){
      const float4* s4 = (const float4*)(cur + ((size_t)n * 128 + grow - 128) * 256 + c4 * 64);
      unsigned int* d = dst + c4 * 32;
#pragma unroll
      for (int j = 0; j < 16; j++){
        float4 f = s4[j];
        d[2 * j]     = pack2(f.x, f.y);
        d[2 * j + 1] = pack2(f.z, f.w);
      }
    } else {
      uint4* d4 = (uint4*)(dst + c4 * 32);
      uint4 z = make_uint4(0, 0, 0, 0);
#pragma unroll
      for (int j = 0; j < 8; j++) d4[j] = z;
    }
    int jr = (grow < 128) ? grow : grow - 128;
    ((uint4*)(dst + 128))[c4] = ((const uint4*)(tem + ((size_t)n * 128 + jr) * 32))[c4];
  }
  __syncthreads();
  int w = t >> 6, lane = t & 63;
  int lrow = lane & 31, khalf = (lane >> 5) * 8;
  int colA = (w * 2) * 32 + lrow, colB = colA + 32;

  // write C-regs -> SB -> coalesced global
  auto store_rc = [&](f32x16 (*acc)[2], const float* bias, unsigned short* out){
    float bs0 = bias[colA], bs1 = bias[colB];
    __syncthreads();
#pragma unroll
    for (int rt = 0; rt < 2; rt++)
#pragma unroll
      for (int reg = 0; reg < 16; reg++){
        int row = rt * 32 + rowmap(reg, lane);
        SB[row * 264 + colA] = f2bf(acc[rt][0][reg] + bs0);
        SB[row * 264 + colB] = f2bf(acc[rt][1][reg] + bs1);
      }
    __syncthreads();
    int r = t >> 2, s = t & 3;
    const uint4* src = (const uint4*)&SB[r * 264 + s * 64];
    uint4* dst = (uint4*)(out + ((size_t)nn * 256 + r0 + r) * 256 + s * 64);
#pragma unroll
    for (int j = 0; j < 8; j++) dst[j] = src[j];
  };

  // ---- pass 1: Q and K share A fragments ----
  {
    f32x16 aq[2][2] = {}, ak[2][2] = {};
    bf16x8 pq0 = ldfrag(&wq[(size_t)colA * 288 + khalf]);
    bf16x8 pq1 = ldfrag(&wq[(size_t)colB * 288 + khalf]);
    bf16x8 pk0 = ldfrag(&wk[(size_t)colA * 288 + khalf]);
    bf16x8 pk1 = ldfrag(&wk[(size_t)colB * 288 + khalf]);
    for (int ks = 0; ks < 18; ks++){
      int koff = ks * 16 + khalf;
      bf16x8 a0 = ldfrag(&A[lrow * 296 + koff]);
      bf16x8 a1 = ldfrag(&A[(32 + lrow) * 296 + koff]);
      bf16x8 q0 = pq0, q1 = pq1, k0 = pk0, k1 = pk1;
      if (ks < 17){
        pq0 = ldfrag(&wq[(size_t)colA * 288 + koff + 16]);
        pq1 = ldfrag(&wq[(size_t)colB * 288 + koff + 16]);
        pk0 = ldfrag(&wk[(size_t)colA * 288 + koff + 16]);
        pk1 = ldfrag(&wk[(size_t)colB * 288 + koff + 16]);
      }
      aq[0][0] = MFMA(a0, q0, aq[0][0]);
      aq[1][0] = MFMA(a1, q0, aq[1][0]);
      aq[0][1] = MFMA(a0, q1, aq[0][1]);
      aq[1][1] = MFMA(a1, q1, aq[1][1]);
      ak[0][0] = MFMA(a0, k0, ak[0][0]);
      ak[1][0] = MFMA(a1, k0, ak[1][0]);
      ak[0][1] = MFMA(a0, k1, ak[0][1]);
      ak[1][1] = MFMA(a1, k1, ak[1][1]);
    }
    store_rc(aq, bq, qb);
    store_rc(ak, bk, kb);
  }

  // ---- pass 2: V (transposed out) ----
  {
    f32x16 av[2][2] = {};
    bf16x8 pv0 = ldfrag(&wv[(size_t)colA * 288 + khalf]);
    bf16x8 pv1 = ldfrag(&wv[(size_t)colB * 288 + khalf]);
    for (int ks = 0; ks < 18; ks++){
      int koff = ks * 16 + khalf;
      bf16x8 a0 = ldfrag(&A[lrow * 296 + koff]);
      bf16x8 a1 = ldfrag(&A[(32 + lrow) * 296 + koff]);
      bf16x8 v0 = pv0, v1 = pv1;
      if (ks < 17){
        pv0 = ldfrag(&wv[(size_t)colA * 288 + koff + 16]);
        pv1 = ldfrag(&wv[(size_t)colB * 288 + koff + 16]);
      }
      av[0][0] = MFMA(a0, v0, av[0][0]);
      av[1][0] = MFMA(a1, v0, av[1][0]);
      av[0][1] = MFMA(a0, v1, av[0][1]);
      av[1][1] = MFMA(a1, v1, av[1][1]);
    }
    float bs0 = bv[colA], bs1 = bv[colB];
    __syncthreads();
#pragma unroll
    for (int rt = 0; rt < 2; rt++)
#pragma unroll
      for (int reg = 0; reg < 16; reg++){
        int kl = rt * 32 + rowmap(reg, lane);
        SB[colA * 66 + kl] = f2bf(av[rt][0][reg] + bs0);
        SB[colB * 66 + kl] = f2bf(av[rt][1][reg] + bs1);
      }
    __syncthreads();
#pragma unroll
    for (int it = 0; it < 8; it++){
      int d = it * 32 + (t >> 3), j = t & 7;
      const unsigned int* vs = (const unsigned int*)&SB[d * 66];
      uint4 val = make_uint4(vs[j * 4], vs[j * 4 + 1], vs[j * 4 + 2], vs[j * 4 + 3]);
      *(uint4*)(vtb + ((size_t)nn * 256 + d) * 256 + r0 + j * 8) = val;
    }
  }
}

// ------------------------------------------------ attention (MFMA, max-free softmax)
__global__ __launch_bounds__(256, 2) void k_attn(const unsigned short* __restrict__ qb,
    const unsigned short* __restrict__ kb, const unsigned short* __restrict__ vtb,
    unsigned short* __restrict__ enc, float* __restrict__ cur,
    const float* __restrict__ tim, int chunk, int lzero){
  __shared__ __align__(16) unsigned short PB[4][32 * 264];
  __shared__ float TS[128];
  int t = threadIdx.x;
  int nn = blockIdx.x >> 1;
  int n  = chunk * 256 + nn;
  int q0 = (blockIdx.x & 1) * 128;
  if (t < 128) TS[t] = tim[(size_t)n * 128 + t];
  __syncthreads();
  int w = t >> 6, lane = t & 63;
  int lrow = lane & 31, khalf = (lane >> 5) * 8;
  int qrow = q0 + w * 32;
  const unsigned short* qn = qb  + (size_t)nn * 65536;
  const unsigned short* kn = kb  + (size_t)nn * 65536;
  const unsigned short* vn = vtb + (size_t)nn * 65536;
  // ---- scores: S = Q K^T (per wave: 32 q x 256 keys)
  f32x16 s[8] = {};
  for (int ks = 0; ks < 16; ks++){
    int koff = ks * 16 + khalf;
    bf16x8 a = ldfrag(&qn[(size_t)(qrow + lrow) * 256 + koff]);
#pragma unroll
    for (int ct = 0; ct < 8; ct++){
      bf16x8 b = ldfrag(&kn[(size_t)(ct * 32 + lrow) * 256 + koff]);
      s[ct] = MFMA(a, b, s[ct]);
    }
  }
  bool tz[8];
#pragma unroll
  for (int ct = 0; ct < 8; ct++)
    tz[ct] = (ct < 4) ? (TS[ct * 32 + lrow] == 0.0f) : false;
  // ---- mask + max-free softmax, P (bf16) -> per-wave LDS
  unsigned short* myP = PB[w];
  bool xw = (qrow < 128);   // wave-uniform
#pragma unroll
  for (int reg = 0; reg < 16; reg++){
    int rl = rowmap(reg, lane);
    int Q = qrow + rl;
    float e[8], sum = 0.0f;
#pragma unroll
    for (int ct = 0; ct < 8; ct++){
      int key = ct * 32 + lrow;
      bool masked;
      if (xw)  masked = (key >= Q) || (key >= 128) || tz[ct];
      else {
        int qq = Q - 128;
        masked = (key < 128) ? ((key >= qq) || tz[ct]) : ((key - 128) != qq);
      }
      e[ct] = masked ? 0.0f : __expf(s[ct][reg] * 0.0625f);
      sum += e[ct];
    }
#pragma unroll
    for (int mk = 1; mk <= 16; mk <<= 1) sum += __shfl_xor(sum, mk, 64);
    float rs = (sum > 0.0f) ? 1.0f / sum : 0.0f;
    float pu = (sum > 0.0f) ? 0.0f : 0.00390625f;   // all-masked row: uniform 1/256
#pragma unroll
    for (int ct = 0; ct < 8; ct++)
      myP[rl * 264 + ct * 32 + lrow] = f2bf(e[ct] * rs + pu);
  }
  // ---- PV (per wave: 32 q x 256 d)
  f32x16 ov[8] = {};
  for (int ks = 0; ks < 16; ks++){
    int koff = ks * 16 + khalf;
    bf16x8 a = ldfrag(&myP[lrow * 264 + koff]);
#pragma unroll
    for (int dt = 0; dt < 8; dt++){
      bf16x8 b = ldfrag(&vn[(size_t)(dt * 32 + lrow) * 256 + koff]);
      ov[dt] = MFMA(a, b, ov[dt]);
    }
  }
  // ---- epilogue
#pragma unroll
  for (int reg = 0; reg < 16; reg++){
    int rl = rowmap(reg, lane);
    int Q = qrow + rl;
    if (xw){
      size_t base = ((size_t)n * 128 + Q) * 256;
#pragma unroll
      for (int dt = 0; dt < 8; dt++)
        enc[base + dt * 32 + lrow] = f2bf(ov[dt][reg]);
    } else {
      int qq = Q - 128;
      float tq = TS[qq];
      size_t base = ((size_t)n * 128 + qq) * 256;
      if (lzero){
#pragma unroll
        for (int dt = 0; dt < 8; dt++){
          float x = ov[dt][reg];
          float ex = __expf(2.0f * x);
          float th = 1.0f - 2.0f / (ex + 1.0f);
          cur[base + dt * 32 + lrow] = (tq > 0.0f) ? th : 0.0f;
        }
      } else if (tq > 0.0f){
#pragma unroll
        for (int dt = 0; dt < 8; dt++){
          float x = ov[dt][reg];
          float ex = __expf(2.0f * x);
          cur[base + dt * 32 + lrow] += 1.0f - 2.0f / (ex + 1.0f);
        }
      }
    }
  }
}

// ------------------------------------------------ save feat (cur at j=L-1)
__global__ __launch_bounds__(256) void k_savefeat(const float* __restrict__ cur,
                                                  float* __restrict__ feat, int h){
  int idx = blockIdx.x * 256 + threadIdx.x;   // 512*256
  int n = idx >> 8, c = idx & 255;
  feat[(size_t)n * 512 + h * 256 + c] = cur[((size_t)n * 128 + 127) * 256 + c];
}

// ------------------------------------------------ output MLP head
__global__ __launch_bounds__(256) void k_mlp(const float* __restrict__ feat,
    const float* __restrict__ w1, const float* __restrict__ b1,
    const float* __restrict__ w2, const float* __restrict__ b2,
    float* __restrict__ out){
  __shared__ float F[512];
  __shared__ float red[4];
  int n = blockIdx.x, t = threadIdx.x;
  F[t]       = feat[(size_t)n * 512 + t];
  F[t + 256] = feat[(size_t)n * 512 + 256 + t];
  __syncthreads();
  float acc = 0.0f;
  for (int k4 = 0; k4 < 128; k4++){
    float b0v = w1[(k4 * 4 + 0) * 256 + t];
    float b1v = w1[(k4 * 4 + 1) * 256 + t];
    float b2v = w1[(k4 * 4 + 2) * 256 + t];
    float b3v = w1[(k4 * 4 + 3) * 256 + t];
    const float4 f = *(const float4*)&F[k4 * 4];
    acc = fmaf(f.x, b0v, fmaf(f.y, b1v, fmaf(f.z, b2v, fmaf(f.w, b3v, acc))));
  }
  acc += b1[t];
  float g = 0.5f * acc * (1.0f + erff(acc * 0.7071067811865475f));
  float part = g * w2[t];
#pragma unroll
  for (int mk = 1; mk < 64; mk <<= 1) part += __shfl_xor(part, mk, 64);
  if ((t & 63) == 0) red[t >> 6] = part;
  __syncthreads();
  if (t == 0) out[n] = red[0] + red[1] + red[2] + red[3] + b2[0];
}

// ------------------------------------------------ launch
extern "C" void kernel_launch(void* const* d_in, const int* in_sizes, int n_in,
                              void* d_out, int out_size, void* d_ws, size_t ws_size,
                              hipStream_t stream){
  const int*   subj = (const int*)  d_in[0];
  const int*   obj  = (const int*)  d_in[1];
  const int*   rel  = (const int*)  d_in[2];
  const float* tim  = (const float*)d_in[3];
  const float* ent  = (const float*)d_in[4];
  const float* rele = (const float*)d_in[5];
  const float* in_w = (const float*)d_in[6];
  const float* in_b = (const float*)d_in[7];
  const float* q_w  = (const float*)d_in[8];
  const float* q_b  = (const float*)d_in[9];
  const float* k_w  = (const float*)d_in[10];
  const float* k_b  = (const float*)d_in[11];
  const float* v_w  = (const float*)d_in[12];
  const float* v_b  = (const float*)d_in[13];
  const float* w1   = (const float*)d_in[14];
  const float* b1   = (const float*)d_in[15];
  const float* w2   = (const float*)d_in[16];
  const float* b2   = (const float*)d_in[17];

  char* ws = (char*)d_ws;                                   // ~208 MiB total
  unsigned short* tem  = (unsigned short*)(ws + 0);         //  4,194,304
  float*          cur  = (float*)(ws + 4194304);            // 67,108,864
  unsigned short* enc  = (unsigned short*)(ws + 71303168);  // 33,554,432
  unsigned short* qb   = (unsigned short*)(ws + 104857600); // 33,554,432
  unsigned short* kb   = (unsigned short*)(ws + 138412032); // 33,554,432
  unsigned short* vtb  = (unsigned short*)(ws + 171966464); // 33,554,432
  float*          feat = (float*)(ws + 205520896);          //  1,048,576
  unsigned short* wT   = (unsigned short*)(ws + 206569472); //  1,966,080
  float* out = (float*)d_out;

  k_wprep<<<3840, 256, 0, stream>>>(in_w, q_w, k_w, v_w, wT);
  k_temporal<<<4096, 256, 0, stream>>>(tim, (unsigned int*)tem);
  k_inproj<<<1024, 256, 0, stream>>>(subj, obj, rel, ent, rele, wT, in_b, enc);

  for (int h = 0; h < 2; h++){
    for (int l = 0; l < 2; l++){
      int o = h * 2 + l;
      int lzero = (l == 0) ? 1 : 0;
      const unsigned short* wq = wT + 98304 + (size_t)(o * 3 + 0) * 73728;
      const unsigned short* wk = wT + 98304 + (size_t)(o * 3 + 1) * 73728;
      const unsigned short* wv = wT + 98304 + (size_t)(o * 3 + 2) * 73728;
      for (int c = 0; c < 2; c++){
        k_qkv<<<1024, 256, 0, stream>>>(enc, cur, tem, wq, wk, wv,
            q_b + o * 256, k_b + o * 256, v_b + o * 256, c, lzero, qb, kb, vtb);
        k_attn<<<512, 256, 0, stream>>>(qb, kb, vtb, enc, cur, tim, c, lzero);
      }
    }
    k_savefeat<<<512, 256, 0, stream>>>(cur, feat, h);
  }
  k_mlp<<<512, 256, 0, stream>>>(feat, w1, b1, w2, b2, out);
}